// Round 6
// baseline (962.781 us; speedup 1.0000x reference)
//
#include <hip/hip_runtime.h>
#include <math.h>

#define NGRAPH 500
#define MP_STEPS 6
#define S2S_STEPS 6
#define S2S_CAP 64

typedef _Float16 h8 __attribute__((ext_vector_type(8)));
typedef float f4 __attribute__((ext_vector_type(4)));

__device__ __forceinline__ float sigmoidf_(float v){ return 1.0f/(1.0f + expf(-v)); }

// ---------------- generic zero fill ----------------
__global__ void k_zero(float* __restrict__ p, int n){
  int i = blockIdx.x*256 + threadIdx.x;
  if(i < n) p[i] = 0.f;
}

// ------- initial node embedding + bias_msg: x = relu(nf@W+b); bm = x @ B2mat -------
// B2mat[d][o] = em_b2[d*64+o] (fp32, exact bias fold for the NNConv message)
__global__ void k_lin0(const float* __restrict__ nf, const float* __restrict__ W,
                       const float* __restrict__ b, const float* __restrict__ B2,
                       float* __restrict__ x, float* __restrict__ bm, int N){
  int n = blockIdx.x*4 + (threadIdx.x >> 6);
  int d = threadIdx.x & 63;
  if(n >= N) return;
  float acc = b[d];
#pragma unroll
  for(int i=0;i<15;i++) acc = fmaf(nf[n*15+i], W[i*64+d], acc);
  float xv = fmaxf(acc, 0.0f);
  x[n*64+d] = xv;
  float bmv = 0.f;
  for(int k=0;k<64;k++){
    float xk = __shfl(xv, k, 64);
    bmv = fmaf(xk, B2[k*64+d], bmv);
  }
  bm[(size_t)n*64+d] = bmv;
}

// ---------------- edge hidden: he[e][0..127] = relu(ef@W1+b1), f16 ----------------
__global__ void k_edgeh(const float* __restrict__ ef, const float* __restrict__ W1,
                        const float* __restrict__ b1, _Float16* __restrict__ he, int E){
  int e = blockIdx.x*2 + (threadIdx.x >> 7);
  int h = threadIdx.x & 127;
  if(e >= E) return;
  float acc = b1[h];
#pragma unroll
  for(int i=0;i<5;i++) acc = fmaf(ef[e*5+i], W1[i*128+h], acc);
  he[(size_t)e*128 + h] = (_Float16)fmaxf(acc, 0.f);
}

// ---------------- W2T[n][k] (f16): em_W2 transposed, K=128 ----------
__global__ void k_prepW2(const float* __restrict__ W2, _Float16* __restrict__ W2T){
  int idx = blockIdx.x*256 + threadIdx.x;
  if(idx >= 4096*128) return;
  int n = idx >> 7, k = idx & 127;
  W2T[idx] = (_Float16)W2[(size_t)k*4096 + n];
}

// ---------------- fused message: agg[dst[e]] += x[src[e]] . (he[e]@W2) + bm[src[e]] ----
// Block = 128 edges, 4 waves. Wave w = o-group (16 cols), 8 M-tiles (all 128 edges).
// Per i: 4 B-frag loads (L2), 32 MFMAs in 8 independent chains (640cyc burst hides L2),
// fp32 x-multiply, register scatter with exact fp32 bias gather.
// VGPR ~210: af[8][4]=128 + g 32 + macc 32. Cap 256 via (256,2) — do NOT tighten (R4!).
__global__ __launch_bounds__(256, 2) void k_fmsg(
    const _Float16* __restrict__ he,   // [E][128]
    const _Float16* __restrict__ W2T,  // [4096][128]
    const float* __restrict__ x,       // [N][64]
    const float* __restrict__ bm,      // [N][64] bias_msg
    const int* __restrict__ src, const int* __restrict__ dst,
    float* __restrict__ agg, int E)
{
  __shared__ _Float16 hs[128*128];   // 32 KB
  __shared__ float xsT[64*132];      // 33.8 KB, xsT[i][edge]
  __shared__ int ds_dst[128];
  __shared__ int ds_src[128];
  const int tid  = threadIdx.x;
  const int og   = tid >> 6;
  const int lane = tid & 63;
  const int quad = lane >> 4;
  const int l15  = lane & 15;
  const int e0   = blockIdx.x * 128;

  // ---- stage he tile: 128 rows x 16 chunks of 16B ----
  for(int t = tid; t < 2048; t += 256){
    int r = t >> 4, c = t & 15;
    uint4 v = make_uint4(0,0,0,0);
    if(e0 + r < E) v = *(const uint4*)&he[(size_t)(e0+r)*128 + c*8];
    *(uint4*)&hs[r*128 + c*8] = v;
  }
  // ---- stage x[src] transposed ----
  {
    int j = tid >> 1, half = tid & 1;
    int sj = (e0 + j < E) ? src[e0 + j] : 0;
    const float4* xr = (const float4*)(x + (size_t)sj*64) + half*8;
#pragma unroll
    for(int k=0;k<8;k++){
      float4 v = xr[k];
      int ib = half*32 + k*4;
      xsT[(ib+0)*132 + j] = v.x;
      xsT[(ib+1)*132 + j] = v.y;
      xsT[(ib+2)*132 + j] = v.z;
      xsT[(ib+3)*132 + j] = v.w;
    }
  }
  if(tid < 128){
    ds_dst[tid] = (e0 + tid < E) ? dst[e0 + tid] : 0;
    ds_src[tid] = (e0 + tid < E) ? src[e0 + tid] : 0;
  }
  __syncthreads();

  // ---- A-frags: 8 M-tiles x 4 K-steps (128 VGPR) ----
  h8 af[8][4];
#pragma unroll
  for(int mt=0;mt<8;mt++)
#pragma unroll
    for(int ks=0;ks<4;ks++)
      af[mt][ks] = *(const h8*)&hs[(mt*16 + l15)*128 + ks*32 + (quad<<3)];

  const _Float16* bbase = W2T + (size_t)(og*16 + l15)*128 + (quad<<3);

  f4 macc[8];
#pragma unroll
  for(int mt=0;mt<8;mt++) macc[mt] = (f4){0.f,0.f,0.f,0.f};

#pragma unroll 1
  for(int i=0;i<64;i++){
    const _Float16* bp = bbase + (size_t)i*64*128;
    h8 bf0 = *(const h8*)(bp);
    h8 bf1 = *(const h8*)(bp + 32);
    h8 bf2 = *(const h8*)(bp + 64);
    h8 bf3 = *(const h8*)(bp + 96);
    f4 g[8];
#pragma unroll
    for(int mt=0;mt<8;mt++) g[mt] = (f4){0.f,0.f,0.f,0.f};
#pragma unroll
    for(int mt=0;mt<8;mt++) g[mt] = __builtin_amdgcn_mfma_f32_16x16x32_f16(af[mt][0], bf0, g[mt], 0,0,0);
#pragma unroll
    for(int mt=0;mt<8;mt++) g[mt] = __builtin_amdgcn_mfma_f32_16x16x32_f16(af[mt][1], bf1, g[mt], 0,0,0);
#pragma unroll
    for(int mt=0;mt<8;mt++) g[mt] = __builtin_amdgcn_mfma_f32_16x16x32_f16(af[mt][2], bf2, g[mt], 0,0,0);
#pragma unroll
    for(int mt=0;mt<8;mt++) g[mt] = __builtin_amdgcn_mfma_f32_16x16x32_f16(af[mt][3], bf3, g[mt], 0,0,0);
#pragma unroll
    for(int mt=0;mt<8;mt++){
      f4 xf = *(const f4*)&xsT[i*132 + mt*16 + (quad<<2)];
      macc[mt] += xf * g[mt];
    }
  }

  // ---- scatter: edge = mt*16+quad*4+r, col = og*16+l15, bias gathered fp32 ----
  const int col = og*16 + l15;
#pragma unroll
  for(int mt=0;mt<8;mt++){
#pragma unroll
    for(int r=0;r<4;r++){
      int edge = mt*16 + (quad<<2) + r;
      if(e0 + edge < E){
        float v = macc[mt][r] + bm[(size_t)ds_src[edge]*64 + col];
        atomicAdd(&agg[(size_t)ds_dst[edge]*64 + col], v);
      }
    }
  }
}

// ---------------- GRU (32 nodes/block) + next-step bias_msg, zeroes agg ----------------
__global__ __launch_bounds__(256) void k_gru2(
    float* __restrict__ x, float* __restrict__ agg, const float* __restrict__ cb,
    const float* __restrict__ WihT, const float* __restrict__ WhhT,   // [64][192]
    const float* __restrict__ bih, const float* __restrict__ bhh,
    const float* __restrict__ B2, float* __restrict__ bm, int N)
{
  __shared__ float ms[32*64], hs2[32*64];
  const int tid = threadIdx.x;
  const int n0 = blockIdx.x*32;
  for(int t=tid; t<2048; t+=256){
    int n = n0 + (t>>6), d = t&63;
    float mv=0.f, hv=0.f;
    if(n < N){
      mv = fmaxf(agg[(size_t)n*64+d] + cb[d], 0.f);
      agg[(size_t)n*64+d] = 0.f;
      hv = x[(size_t)n*64+d];
    }
    ms[t]=mv; hs2[t]=hv;
  }
  __syncthreads();
  const int gx = tid & 31, ng = tid >> 5;
  float ar[4][2]={{0}}, az[4][2]={{0}}, anx[4][2]={{0}}, anh[4][2]={{0}};
#pragma unroll 4
  for(int k=0;k<64;k++){
    float wi0=WihT[k*192+gx],     wi1=WihT[k*192+gx+32];
    float wi2=WihT[k*192+gx+64],  wi3=WihT[k*192+gx+96];
    float wi4=WihT[k*192+gx+128], wi5=WihT[k*192+gx+160];
    float wh0=WhhT[k*192+gx],     wh1=WhhT[k*192+gx+32];
    float wh2=WhhT[k*192+gx+64],  wh3=WhhT[k*192+gx+96];
    float wh4=WhhT[k*192+gx+128], wh5=WhhT[k*192+gx+160];
#pragma unroll
    for(int j=0;j<4;j++){
      float mk = ms[(ng*4+j)*64+k], hk = hs2[(ng*4+j)*64+k];
      ar[j][0] = fmaf(mk,wi0, fmaf(hk,wh0, ar[j][0]));
      ar[j][1] = fmaf(mk,wi1, fmaf(hk,wh1, ar[j][1]));
      az[j][0] = fmaf(mk,wi2, fmaf(hk,wh2, az[j][0]));
      az[j][1] = fmaf(mk,wi3, fmaf(hk,wh3, az[j][1]));
      anx[j][0]= fmaf(mk,wi4, anx[j][0]);
      anx[j][1]= fmaf(mk,wi5, anx[j][1]);
      anh[j][0]= fmaf(hk,wh4, anh[j][0]);
      anh[j][1]= fmaf(hk,wh5, anh[j][1]);
    }
  }
  float xn[4][2];
#pragma unroll
  for(int j=0;j<4;j++){
#pragma unroll
    for(int c=0;c<2;c++){
      int d = gx + 32*c;
      float r  = sigmoidf_(ar[j][c] + bih[d]     + bhh[d]);
      float z  = sigmoidf_(az[j][c] + bih[64+d]  + bhh[64+d]);
      float nn = tanhf(anx[j][c] + bih[128+d] + r*(anh[j][c] + bhh[128+d]));
      float hv = hs2[(ng*4+j)*64+d];
      xn[j][c] = (1.f - z)*nn + z*hv;
    }
  }
  __syncthreads();   // done reading ms/hs2
#pragma unroll
  for(int j=0;j<4;j++){
#pragma unroll
    for(int c=0;c<2;c++){
      int n = n0 + ng*4 + j;
      ms[(ng*4+j)*64 + gx + 32*c] = xn[j][c];
      if(n < N) x[(size_t)n*64 + gx + 32*c] = xn[j][c];
    }
  }
  __syncthreads();
  // bias_msg for next step: bm[n][o] = sum_d xnew[n][d] * B2[d][o]
  float bmv[4][2] = {{0}};
#pragma unroll 4
  for(int d=0;d<64;d++){
    float b0 = B2[d*64+gx], b1 = B2[d*64+gx+32];
#pragma unroll
    for(int j=0;j<4;j++){
      float xd = ms[(ng*4+j)*64 + d];
      bmv[j][0] = fmaf(xd, b0, bmv[j][0]);
      bmv[j][1] = fmaf(xd, b1, bmv[j][1]);
    }
  }
#pragma unroll
  for(int j=0;j<4;j++){
    int n = n0 + ng*4 + j;
    if(n < N){
      bm[(size_t)n*64 + gx]      = bmv[j][0];
      bm[(size_t)n*64 + gx + 32] = bmv[j][1];
    }
  }
}

// ---------------- weight transposes ----------------
__global__ void k_tr_gru(const float* __restrict__ Wih, const float* __restrict__ Whh,
                         float* __restrict__ WihT, float* __restrict__ WhhT){
  int idx = blockIdx.x*256 + threadIdx.x;
  if(idx < 192*64){
    int r = idx/64, i = idx%64;
    WihT[i*192 + r] = Wih[idx];
    WhhT[i*192 + r] = Whh[idx];
  }
}

__global__ void k_tr_lstm(const float* __restrict__ w0ih, const float* __restrict__ w0hh,
                          const float* __restrict__ w12ih, const float* __restrict__ w12hh,
                          float* __restrict__ t0ih, float* __restrict__ t0hh,
                          float* __restrict__ t12ih, float* __restrict__ t12hh){
  int idx = blockIdx.x*256 + threadIdx.x;
  if(idx < 256*128){ int r = idx/128, k = idx%128; t0ih[k*256+r] = w0ih[idx]; }
  if(idx < 256*64){ int r = idx/64, k = idx%64; t0hh[k*256+r] = w0hh[idx]; }
  if(idx < 2*256*64){
    int l = idx/(256*64); int rem = idx%(256*64); int r = rem/64, k = rem%64;
    t12ih[l*64*256 + k*256 + r] = w12ih[idx];
    t12hh[l*64*256 + k*256 + r] = w12hh[idx];
  }
}

// ---------------- fused Set2Set + head (512 threads, split-K gates) ----------------
__device__ __forceinline__ int lbound(const int* __restrict__ a, int n, int v){
  int lo=0, hi=n;
  while(lo<hi){ int mid=(lo+hi)>>1; if(a[mid]<v) lo=mid+1; else hi=mid; }
  return lo;
}

template<int IN>
__device__ __forceinline__ void lstm_layer2(
    const float* __restrict__ xin, float* __restrict__ hv, float* __restrict__ cv,
    const float* __restrict__ WihT, const float* __restrict__ WhhT,
    const float* __restrict__ bi, const float* __restrict__ bh,
    float* __restrict__ gpart, int tid, int t, int hf)
{
  const int kx0 = hf*(IN/2);
  const int kh0 = hf*32;
  float a0=0.f,a1=0.f,a2=0.f,a3=0.f;
#pragma unroll
  for(int k=0;k<IN/2;k+=4){
    a0 = fmaf(xin[kx0+k+0], WihT[(kx0+k+0)*256+t], a0);
    a1 = fmaf(xin[kx0+k+1], WihT[(kx0+k+1)*256+t], a1);
    a2 = fmaf(xin[kx0+k+2], WihT[(kx0+k+2)*256+t], a2);
    a3 = fmaf(xin[kx0+k+3], WihT[(kx0+k+3)*256+t], a3);
  }
#pragma unroll
  for(int k=0;k<32;k+=4){
    a0 = fmaf(hv[kh0+k+0], WhhT[(kh0+k+0)*256+t], a0);
    a1 = fmaf(hv[kh0+k+1], WhhT[(kh0+k+1)*256+t], a1);
    a2 = fmaf(hv[kh0+k+2], WhhT[(kh0+k+2)*256+t], a2);
    a3 = fmaf(hv[kh0+k+3], WhhT[(kh0+k+3)*256+t], a3);
  }
  gpart[tid] = (a0+a1)+(a2+a3);
  __syncthreads();
  if(tid < 64){
    float gi = gpart[tid]     + gpart[256+tid] + bi[tid]     + bh[tid];
    float gf = gpart[64+tid]  + gpart[320+tid] + bi[64+tid]  + bh[64+tid];
    float gg = gpart[128+tid] + gpart[384+tid] + bi[128+tid] + bh[128+tid];
    float go = gpart[192+tid] + gpart[448+tid] + bi[192+tid] + bh[192+tid];
    float cn = sigmoidf_(gf)*cv[tid] + sigmoidf_(gi)*tanhf(gg);
    cv[tid] = cn;
    hv[tid] = sigmoidf_(go)*tanhf(cn);
  }
  __syncthreads();
}

__global__ __launch_bounds__(512) void k_s2s(
    const float* __restrict__ x, const int* __restrict__ gid, int N,
    const float* __restrict__ t0ih, const float* __restrict__ t0hh,
    const float* __restrict__ l0_bih, const float* __restrict__ l0_bhh,
    const float* __restrict__ t12ih, const float* __restrict__ t12hh,
    const float* __restrict__ l12_bih, const float* __restrict__ l12_bhh,
    const float* __restrict__ W1, const float* __restrict__ b1,
    const float* __restrict__ W2, const float* __restrict__ b2,
    float* __restrict__ y)
{
  const int b = blockIdx.x;
  const int tid = threadIdx.x;
  const int t = tid & 255, hf = tid >> 8;
  const int wave = tid >> 6, lane = tid & 63;
  __shared__ float xt[S2S_CAP*64];
  __shared__ float hsl[3][64], csl[3][64], qs[128], gpart[512];
  __shared__ float ps[S2S_CAP], rop[8*64], wred[8], wsum[8];
  __shared__ int sh_n0, sh_n1;

  if(tid == 0) sh_n0 = lbound(gid, N, b);
  if(tid == 1) sh_n1 = lbound(gid, N, b+1);
  if(tid < 192){ hsl[tid>>6][tid&63] = 0.f; csl[tid>>6][tid&63] = 0.f; }
  if(tid >= 192 && tid < 320) qs[tid-192] = 0.f;
  __syncthreads();
  const int n0 = sh_n0, cnt = sh_n1 - sh_n0;
  const int cc = (cnt < S2S_CAP) ? cnt : S2S_CAP;

  for(int j = wave; j < cc; j += 8)
    xt[j*64 + lane] = x[(size_t)(n0+j)*64 + lane];
  __syncthreads();

  for(int step=0; step<S2S_STEPS; step++){
    lstm_layer2<128>(qs,     hsl[0], csl[0], t0ih,           t0hh,           l0_bih,        l0_bhh,        gpart, tid, t, hf);
    lstm_layer2<64>(hsl[0],  hsl[1], csl[1], t12ih,          t12hh,          l12_bih,       l12_bhh,       gpart, tid, t, hf);
    lstm_layer2<64>(hsl[1],  hsl[2], csl[2], t12ih + 64*256, t12hh + 64*256, l12_bih + 256, l12_bhh + 256, gpart, tid, t, hf);

    // ---- attention pass 1: dots (cached in ps) + max ----
    float qv = hsl[2][lane];
    float pm = -1e30f;
    for(int j = wave; j < cc; j += 8){
      float p = xt[j*64 + lane] * qv;
#pragma unroll
      for(int o=32;o;o>>=1) p += __shfl_xor(p, o, 64);
      if(lane == 0) ps[j] = p;
      pm = fmaxf(pm, p);
    }
    for(int j = S2S_CAP + wave; j < cnt; j += 8){   // fallback (never for this input)
      float p = x[(size_t)(n0+j)*64 + lane] * qv;
#pragma unroll
      for(int o=32;o;o>>=1) p += __shfl_xor(p, o, 64);
      pm = fmaxf(pm, p);
    }
    if(lane == 0) wred[wave] = pm;
    __syncthreads();
    float mx = wred[0];
#pragma unroll
    for(int w=1;w<8;w++) mx = fmaxf(mx, wred[w]);

    // ---- pass 2: exp/sum/weighted accumulate ----
    float pro = 0.f, pssum = 0.f;
    for(int j = wave; j < cc; j += 8){
      float ex = expf(ps[j] - mx);
      pssum += ex;
      pro = fmaf(ex, xt[j*64 + lane], pro);
    }
    for(int j = S2S_CAP + wave; j < cnt; j += 8){
      float xv = x[(size_t)(n0+j)*64 + lane];
      float p = xv * qv;
#pragma unroll
      for(int o=32;o;o>>=1) p += __shfl_xor(p, o, 64);
      float ex = expf(p - mx);
      pssum += ex;
      pro = fmaf(ex, xv, pro);
    }
    rop[wave*64 + lane] = pro;
    if(lane == 0) wsum[wave] = pssum;
    __syncthreads();
    if(tid < 64){
      float tot = 0.f;
#pragma unroll
      for(int w=0;w<8;w++) tot += wsum[w];
      float inv = (tot > 0.f) ? 1.f/tot : 0.f;
      float rv = 0.f;
#pragma unroll
      for(int w=0;w<8;w++) rv += rop[w*64+tid];
      qs[tid] = hsl[2][tid];
      qs[64+tid] = rv * inv;
    }
    __syncthreads();
  }
  // ---- head ----
  if(tid < 64){
    float a = b1[tid];
#pragma unroll 4
    for(int k=0;k<128;k++) a = fmaf(qs[k], W1[k*64+tid], a);
    gpart[tid] = fmaxf(a, 0.f);
  }
  __syncthreads();
  if(tid < 12){
    float o = b2[tid];
#pragma unroll 4
    for(int k=0;k<64;k++) o = fmaf(gpart[k], W2[k*12+tid], o);
    y[b*12+tid] = o;
  }
}

extern "C" void kernel_launch(void* const* d_in, const int* in_sizes, int n_in,
                              void* d_out, int out_size, void* d_ws, size_t ws_size,
                              hipStream_t stream) {
  const float* node_feat = (const float*)d_in[0];
  const float* edge_feat = (const float*)d_in[1];
  const int*   src       = (const int*)d_in[2];
  const int*   dst       = (const int*)d_in[3];
  const int*   gid       = (const int*)d_in[4];
  const float* lin0_W = (const float*)d_in[6];
  const float* lin0_b = (const float*)d_in[7];
  const float* em_W1  = (const float*)d_in[8];
  const float* em_b1  = (const float*)d_in[9];
  const float* em_W2  = (const float*)d_in[10];
  const float* em_b2  = (const float*)d_in[11];
  const float* conv_b = (const float*)d_in[12];
  const float* gru_Wih = (const float*)d_in[13];
  const float* gru_Whh = (const float*)d_in[14];
  const float* gru_bih = (const float*)d_in[15];
  const float* gru_bhh = (const float*)d_in[16];
  const float* l0_Wih = (const float*)d_in[17];
  const float* l0_Whh = (const float*)d_in[18];
  const float* l0_bih = (const float*)d_in[19];
  const float* l0_bhh = (const float*)d_in[20];
  const float* l12_Wih = (const float*)d_in[21];
  const float* l12_Whh = (const float*)d_in[22];
  const float* l12_bih = (const float*)d_in[23];
  const float* l12_bhh = (const float*)d_in[24];
  const float* lin1_W = (const float*)d_in[25];
  const float* lin1_b = (const float*)d_in[26];
  const float* lin2_W = (const float*)d_in[27];
  const float* lin2_b = (const float*)d_in[28];
  float* y = (float*)d_out;

  const int N = in_sizes[0] / 15;
  const int E = in_sizes[1] / 5;
  const int B = NGRAPH;

  char* p = (char*)d_ws;
  auto carve = [&](size_t bytes)->char* {
    char* r = p; p += (bytes + 255) & ~(size_t)255; return r;
  };
  _Float16* he_h = (_Float16*)carve((size_t)E*128*2);
  _Float16* W2T  = (_Float16*)carve((size_t)4096*128*2);
  float* x     = (float*)carve((size_t)N*64*4);
  float* agg   = (float*)carve((size_t)N*64*4);
  float* bmv   = (float*)carve((size_t)N*64*4);
  float* gWihT = (float*)carve(192*64*4);
  float* gWhhT = (float*)carve(192*64*4);
  float* t0ih  = (float*)carve(128*256*4);
  float* t0hh  = (float*)carve(64*256*4);
  float* t12ih = (float*)carve(2*64*256*4);
  float* t12hh = (float*)carve(2*64*256*4);
  (void)ws_size; (void)n_in; (void)out_size;

  // ---- prep ----
  k_lin0<<<(N+3)/4, 256, 0, stream>>>(node_feat, lin0_W, lin0_b, em_b2, x, bmv, N);
  k_edgeh<<<(E+1)/2, 256, 0, stream>>>(edge_feat, em_W1, em_b1, he_h, E);
  k_prepW2<<<(4096*128+255)/256, 256, 0, stream>>>(em_W2, W2T);
  k_tr_gru<<<(192*64+255)/256, 256, 0, stream>>>(gru_Wih, gru_Whh, gWihT, gWhhT);
  k_tr_lstm<<<(2*256*64+255)/256, 256, 0, stream>>>(l0_Wih, l0_Whh, l12_Wih, l12_Whh,
                                                    t0ih, t0hh, t12ih, t12hh);
  k_zero<<<(N*64+255)/256, 256, 0, stream>>>(agg, N*64);

  // ---- message passing (k_gru2 zeroes agg + writes next bias_msg) ----
  const int nblk = (E + 127) / 128;
  for(int s=0; s<MP_STEPS; s++){
    k_fmsg<<<nblk, 256, 0, stream>>>(he_h, W2T, x, bmv, src, dst, agg, E);
    k_gru2<<<(N+31)/32, 256, 0, stream>>>(x, agg, conv_b, gWihT, gWhhT,
                                          gru_bih, gru_bhh, em_b2, bmv, N);
  }

  // ---- fused set2set + head ----
  k_s2s<<<B, 512, 0, stream>>>(x, gid, N,
                               t0ih, t0hh, l0_bih, l0_bhh,
                               t12ih, t12hh, l12_bih, l12_bhh,
                               lin1_W, lin1_b, lin2_W, lin2_b, y);
}